// Round 6
// baseline (1174.574 us; speedup 1.0000x reference)
//
#include <hip/hip_runtime.h>

typedef float f32x4 __attribute__((ext_vector_type(4)));
typedef short short8 __attribute__((ext_vector_type(8)));
typedef short s16x4 __attribute__((ext_vector_type(4)));

#define MFMA16(a, b, c) __builtin_amdgcn_mfma_f32_16x16x32_bf16((a), (b), (c), 0, 0, 0)

#define T_ 256
#define B_ 1024
#define H_ 128
#define TB_ 262144
#define BH_ 131072
#define LOG2PI_F 1.8378770664093453f
#define LN2_F 0.6931471805599453f
#define LOG2E_F 1.4426950408889634f

__device__ inline short f2bf(float f) {
    unsigned u = __builtin_bit_cast(unsigned, f);
    u += 0x7fffu + ((u >> 16) & 1u);
    return (short)(u >> 16);
}
__device__ inline float fexp(float x) { return __builtin_amdgcn_exp2f(x * LOG2E_F); }
__device__ inline float fsigm(float x) { return __builtin_amdgcn_rcpf(1.f + fexp(-x)); }
__device__ inline float ftanh(float x) { return 1.f - 2.f * __builtin_amdgcn_rcpf(fexp(2.f * x) + 1.f); }

__device__ inline short8 pack8(float4 u0, float4 u1) {
    short8 p;
    p[0] = f2bf(u0.x); p[1] = f2bf(u0.y); p[2] = f2bf(u0.z); p[3] = f2bf(u0.w);
    p[4] = f2bf(u1.x); p[5] = f2bf(u1.y); p[6] = f2bf(u1.z); p[7] = f2bf(u1.w);
    return p;
}

// encoder layer on a 16-row (4b x 4t) tile, weights in registers (per ex-wave 16-col slice).
// Bitwise-identical math to the old ex_kernel (bf16 MFMA, bias in C-init, ftanh, f2bf).
__device__ __forceinline__ void enc_layer_reg(
    const short* inb, const short8* fw, float bias, short* outb,
    int l15, int kg, int ew)
{
    const int xsw = (l15 & 7) << 3;
    short8 a[4];
#pragma unroll
    for (int kk = 0; kk < 4; ++kk)
        a[kk] = *(const short8*)&inb[l15 * 160 + ((kk * 32 + kg * 8) ^ xsw)];
    f32x4 acc = {bias, bias, bias, bias};
#pragma unroll
    for (int kk = 0; kk < 4; ++kk) acc = MFMA16(a[kk], fw[kk], acc);
#pragma unroll
    for (int j = 0; j < 4; ++j) {
        const int row = kg * 4 + j;
        outb[row * 160 + ((ew * 16 + l15) ^ ((row & 7) << 3))] = f2bf(ftanh(acc[j]));
    }
}

// ---------------- fully-fused: encoder (producer waves) + LSTM + heads + logprob ----------------
// 1024 threads = 16 waves: waves 0-7 = LSTM consumers (as before), waves 8-15 = encoder
// producers. Per 4-step group g, ex waves build group g+2's x2 tile entirely in LDS:
// t0 stage obs (reg-prefetched 1 group ahead), t1 layer1, t2 layer2 -> x2b[g&1], t3 idle.
// They share the per-step barriers, so the scan's critical path only gains whatever their
// small bursts can't hide in the 23% idle pipe slots. No x2p global round-trip, no ex_kernel.
__global__ __launch_bounds__(1024, 4) void fused_kernel(
    const float* __restrict__ obs,
    const float* __restrict__ whh, const float* __restrict__ wih,
    const float* __restrict__ h0, const float* __restrict__ c0,
    const float* __restrict__ bhh, const float* __restrict__ bih,
    const float* __restrict__ dones,
    const float* __restrict__ amw, const float* __restrict__ crw,
    const float* __restrict__ amb, const float* __restrict__ crb,
    const float* __restrict__ w1f, const float* __restrict__ eb1,
    const float* __restrict__ w2f, const float* __restrict__ eb2,
    const float* __restrict__ lstd, const float* __restrict__ actions,
    float* __restrict__ out)
{
    __shared__ __align__(16) short hbuf[2][4 * 160];   // masked h dbuf (MFMA A source)
    __shared__ __align__(16) short hring[16 * 640];    // unmasked h2 ring [slot][4*160]
    __shared__ __align__(16) short x2b[2][16 * 160];   // x2 group slots (XOR-swizzled)
    __shared__ __align__(16) short obsb[16 * 160];     // obs tile (4b x 4t) bf16
    __shared__ __align__(16) short x1b[16 * 160];      // x1 tile
    __shared__ float dlds[1028];                       // masks [t][j]
    __shared__ float hd[1024 * 12];                    // head results [t*4+kg][12] f32 (48KB)
    const int tid = threadIdx.x;
    const int l = tid & 63, w = tid >> 6;              // 16 waves
    const int l15 = l & 15, kg = l >> 4;
    const int b0 = blockIdx.x * 4;
    const int d = w * 16 + l15;                        // valid for lstm waves (w<8)
    const int ew = w & 7;                              // ex-wave col-slice id
    const int xsw = (l15 & 7) << 3;

    // ---- role-specific persistent registers ----
    short8 bfr[4][4], bfi[4][4], hb4[4];               // lstm waves
    short8 fw1r[4], fw2r[4];                           // ex waves
    float bh[4], biasH = 0.f, bb1 = 0.f, bb2 = 0.f;
    float h = 0.f, c = 0.f;
    float4 r0, r1, opf;

    // ex staging ids: thread owns one float4: row = ej*4 + et (batch-major)
    const int tid2 = tid & 511;
    const int et = tid2 >> 7, ej = (tid2 >> 5) & 3, edim = (tid2 & 31) * 4;
    const int erow = ej * 4 + et;
    const int elds = erow * 160 + (edim ^ ((erow & 7) << 3));
#define OBSIDX(G) ((((size_t)(((G) * 4 + et) <= 255 ? ((G) * 4 + et) : 255)) * 1024 + b0 + ej) * 128 + edim)
#define STAGE_OBS(V)                                                                       \
    {                                                                                      \
        s16x4 p;                                                                           \
        p[0] = f2bf((V).x); p[1] = f2bf((V).y); p[2] = f2bf((V).z); p[3] = f2bf((V).w);    \
        *(s16x4*)&obsb[elds] = p;                                                          \
    }

    if (w >= 8) {
        // encoder weights -> regs (16-col slice per wave), issue obs g0/g1 loads
        r0 = *(const float4*)(obs + OBSIDX(0));
        r1 = *(const float4*)(obs + OBSIDX(1));
#pragma unroll
        for (int kk = 0; kk < 4; ++kk) {
            const float* s1 = w1f + (ew * 16 + l15) * 128 + kk * 32 + 8 * kg;
            const float* s2 = w2f + (ew * 16 + l15) * 128 + kk * 32 + 8 * kg;
            fw1r[kk] = pack8(*(const float4*)s1, *(const float4*)(s1 + 4));
            fw2r[kk] = pack8(*(const float4*)s2, *(const float4*)(s2 + 4));
            asm volatile("" : "+v"(fw1r[kk]), "+v"(fw2r[kk]));
        }
        bb1 = eb1[ew * 16 + l15];
        bb2 = eb2[ew * 16 + l15];
    } else {
        // persistent w_hh + w_ih B-frags, converted in-reg from f32 (+ anti-remat pin)
#pragma unroll
        for (int s = 0; s < 4; ++s)
#pragma unroll
            for (int kk = 0; kk < 4; ++kk) {
                const float* sr = whh + ((s * 128 + d) * 128 + kk * 32 + 8 * kg);
                const float* si = wih + ((s * 128 + d) * 128 + kk * 32 + 8 * kg);
                bfr[s][kk] = pack8(*(const float4*)sr, *(const float4*)(sr + 4));
                bfi[s][kk] = pack8(*(const float4*)si, *(const float4*)(si + 4));
                asm volatile("" : "+v"(bfr[s][kk]), "+v"(bfi[s][kk]));
            }
        // head B-frags: row l15: 0 = cr_w, 1..8 = am_w[l15-1], 9..15 = 0
#pragma unroll
        for (int kk = 0; kk < 4; ++kk) {
            if (l15 == 0) {
                const float* s0 = crw + kk * 32 + 8 * kg;
                hb4[kk] = pack8(*(const float4*)s0, *(const float4*)(s0 + 4));
            } else if (l15 <= 8) {
                const float* s0 = amw + (l15 - 1) * 128 + kk * 32 + 8 * kg;
                hb4[kk] = pack8(*(const float4*)s0, *(const float4*)(s0 + 4));
            } else {
                hb4[kk] = short8{0, 0, 0, 0, 0, 0, 0, 0};
            }
            asm volatile("" : "+v"(hb4[kk]));
        }
        biasH = (l15 == 0) ? crb[0] : (l15 <= 8 ? amb[l15 - 1] : 0.f);
#pragma unroll
        for (int s = 0; s < 4; ++s) bh[s] = bhh[s * 128 + d] + bih[s * 128 + d];
        h = h0[(b0 + kg) * 128 + d];
        c = c0[(b0 + kg) * 128 + d];
    }

    for (int i = tid; i < 1028; i += 1024) {
        int t = i >> 2, jj = i & 3;
        dlds[i] = (t < 256) ? 1.f - dones[t * 1024 + b0 + jj] : 1.f;
    }

    // ---- prologue: encode g0 -> x2b[0], g1 -> x2b[1]; prefetch obs g2 ----
    if (w >= 8) STAGE_OBS(r0);
    __syncthreads();
    if (w >= 8) enc_layer_reg(obsb, fw1r, bb1, x1b, l15, kg, ew);
    __syncthreads();
    if (w >= 8) enc_layer_reg(x1b, fw2r, bb2, &x2b[0][0], l15, kg, ew);
    __syncthreads();
    if (w >= 8) {
        STAGE_OBS(r1);
        opf = *(const float4*)(obs + OBSIDX(2));
    }
    __syncthreads();
    if (w >= 8) enc_layer_reg(obsb, fw1r, bb1, x1b, l15, kg, ew);
    __syncthreads();

    f32x4 xgA[4], xgB[4];
    const int aoff = (l15 >> 2) * 160;  // quad-replicated A rows: batch = row>>2
    if (w >= 8) {
        enc_layer_reg(x1b, fw2r, bb2, &x2b[1][0], l15, kg, ew);
    } else {
        // prologue x-chains for g0 (x2b[0] stable since 3 barriers ago)
#pragma unroll
        for (int s = 0; s < 4; ++s) {
            short8 ax[4];
#pragma unroll
            for (int kk = 0; kk < 4; ++kk)
                ax[kk] = *(const short8*)&x2b[0][l15 * 160 + ((kk * 32 + kg * 8) ^ xsw)];
            f32x4 accX = {bh[s], bh[s], bh[s], bh[s]};
#pragma unroll
            for (int kk = 0; kk < 4; ++kk) accX = MFMA16(ax[kk], bfi[s][kk], accX);
            xgA[s] = accX;
        }
        hbuf[0][kg * 160 + d] = f2bf(h * dlds[kg]);
    }
    asm volatile("s_waitcnt lgkmcnt(0)" ::: "memory");
    __syncthreads();

    float mreg = dlds[kg];

    // one step; lstm waves: h-MFMA + x-chain + (head); ex waves: enc phase EPH
    // EPH: 1 = stage obs (g+2 tile) + issue load GNEXT, 2 = layer1, 3 = layer2 -> x2W, 0 = idle
#define STEP(t, hb, i_s, xgC, xgN, x2R, x2W, EPH, GNEXT, DO_HEAD)                          \
    {                                                                                      \
        if (w < 8) {                                                                       \
            short8 a[4];                                                                   \
            _Pragma("unroll")                                                              \
            for (int kk = 0; kk < 4; ++kk)                                                 \
                a[kk] = *(const short8*)&hbuf[hb][aoff + kk * 32 + kg * 8];                \
            f32x4 acc[4];                                                                  \
            _Pragma("unroll")                                                              \
            for (int s = 0; s < 4; ++s) acc[s] = xgC[s];                                   \
            _Pragma("unroll")                                                              \
            for (int kk = 0; kk < 4; ++kk)                                                 \
                _Pragma("unroll")                                                          \
                for (int s = 0; s < 4; ++s) acc[s] = MFMA16(a[kk], bfr[s][kk], acc[s]);    \
            {                                                                              \
                short8 ax[4];                                                              \
                _Pragma("unroll")                                                          \
                for (int kk = 0; kk < 4; ++kk)                                             \
                    ax[kk] = *(const short8*)&x2R[l15 * 160 + ((kk * 32 + kg * 8) ^ xsw)]; \
                f32x4 accX = {bh[i_s], bh[i_s], bh[i_s], bh[i_s]};                         \
                _Pragma("unroll")                                                          \
                for (int kk = 0; kk < 4; ++kk) accX = MFMA16(ax[kk], bfi[i_s][kk], accX);  \
                xgN[i_s] = accX;                                                           \
            }                                                                              \
            if (DO_HEAD) {                                                                 \
                int th = (t) - 8 + w;                                                      \
                const short* hr = &hring[(th & 15) * 640];                                 \
                short8 ah[4];                                                              \
                _Pragma("unroll")                                                          \
                for (int kk = 0; kk < 4; ++kk)                                             \
                    ah[kk] = *(const short8*)&hr[aoff + kk * 32 + kg * 8];                 \
                f32x4 aH = {biasH, biasH, biasH, biasH};                                   \
                _Pragma("unroll")                                                          \
                for (int kk = 0; kk < 4; ++kk) aH = MFMA16(ah[kk], hb4[kk], aH);           \
                if (l15 < 9) hd[((th) * 4 + kg) * 12 + l15] = aH[0];                       \
            }                                                                              \
            float mn = dlds[((t) + 1) * 4 + kg];                                           \
            float gi = acc[0][i_s];                                                        \
            float gf = acc[1][i_s];                                                        \
            float gg = acc[2][i_s];                                                        \
            float go = acc[3][i_s];                                                        \
            c = fsigm(gf) * (c * mreg) + fsigm(gi) * ftanh(gg);                            \
            float h2 = fsigm(go) * ftanh(c);                                               \
            h = h2;                                                                        \
            mreg = mn;                                                                     \
            hbuf[(hb) ^ 1][kg * 160 + d] = f2bf(h2 * mn);                                  \
            hring[((t) & 15) * 640 + kg * 160 + d] = f2bf(h2);                             \
        } else {                                                                           \
            if ((EPH) == 1) {                                                              \
                STAGE_OBS(opf);                                                            \
                opf = *(const float4*)(obs + OBSIDX(GNEXT));                               \
            } else if ((EPH) == 2) {                                                       \
                enc_layer_reg(obsb, fw1r, bb1, x1b, l15, kg, ew);                          \
            } else if ((EPH) == 3) {                                                       \
                enc_layer_reg(x1b, fw2r, bb2, x2W, l15, kg, ew);                           \
            }                                                                              \
        }                                                                                  \
        asm volatile("s_waitcnt lgkmcnt(0)" ::: "memory");                                 \
        __builtin_amdgcn_s_barrier();                                                      \
        asm volatile("" ::: "memory");                                                     \
    }

    for (int g = 0; g < 64; g += 2) {
        {   // even group g: consume xgA, produce xgB from x2b[1]; ex builds g+2 -> x2b[0]
            const int tb = g * 4;
            const short* x2R = &x2b[1][0];
            short* x2W = &x2b[0][0];
            STEP(tb + 0, 0, 0, xgA, xgB, x2R, x2W, 1, (g + 3), (g > 0));
            STEP(tb + 1, 1, 1, xgA, xgB, x2R, x2W, 2, 0, 0);
            STEP(tb + 2, 0, 2, xgA, xgB, x2R, x2W, 3, 0, 0);
            STEP(tb + 3, 1, 3, xgA, xgB, x2R, x2W, 0, 0, 0);
        }
        {   // odd group g+1: consume xgB, produce xgA from x2b[0]; ex builds g+3 -> x2b[1]
            const int tb = (g + 1) * 4;
            const short* x2R = &x2b[0][0];
            short* x2W = &x2b[1][0];
            STEP(tb + 0, 0, 0, xgB, xgA, x2R, x2W, 1, (g + 4), 0);
            STEP(tb + 1, 1, 1, xgB, xgA, x2R, x2W, 2, 0, 0);
            STEP(tb + 2, 0, 2, xgB, xgA, x2R, x2W, 3, 0, 0);
            STEP(tb + 3, 1, 3, xgB, xgA, x2R, x2W, 0, 0, 0);
        }
    }
#undef STEP
#undef STAGE_OBS
#undef OBSIDX

    if (w < 8) {
        // final heads for t = 248..255 (ring slots 8..15), one step per wave
        int th = 248 + w;
        const short* hr = &hring[(th & 15) * 640];
        short8 ah[4];
#pragma unroll
        for (int kk = 0; kk < 4; ++kk)
            ah[kk] = *(const short8*)&hr[aoff + kk * 32 + kg * 8];
        f32x4 aH = {biasH, biasH, biasH, biasH};
#pragma unroll
        for (int kk = 0; kk < 4; ++kk) aH = MFMA16(ah[kk], hb4[kk], aH);
        if (l15 < 9) hd[(th * 4 + kg) * 12 + l15] = aH[0];

        out[3 * TB_ + (b0 + kg) * 128 + d] = h;
        out[3 * TB_ + BH_ + (b0 + kg) * 128 + d] = c;
    }

    // ---- fused logprob/entropy/value epilogue: 1024 threads, one row each ----
    __syncthreads();
    {
        const int rr = tid;                    // 0..1023 = [t][bb]
        const int t = rr >> 2, bb = rr & 3;
        const float* hp = &hd[rr * 12];
        const float* ap = actions + ((size_t)t * 1024 + b0 + bb) * 8;
        float4 a0 = *(const float4*)(ap);
        float4 a1 = *(const float4*)(ap + 4);
        float act[8] = {a0.x, a0.y, a0.z, a0.w, a1.x, a1.y, a1.z, a1.w};
        float lp = 0.f, lj = 0.f, entS = 0.f;
#pragma unroll
        for (int ai = 0; ai < 8; ++ai) {
            float x = act[ai];
            float xc = fminf(fmaxf(x, -1.f + 1e-6f), 1.f - 1e-6f);
            float u = 0.5f * LN2_F *
                      (__builtin_amdgcn_logf(1.f + xc) - __builtin_amdgcn_logf(1.f - xc));
            float ls = lstd[ai];
            float z = (u - hp[1 + ai]) * fexp(-ls);
            lp += -0.5f * z * z - ls;
            lj += LN2_F * __builtin_amdgcn_logf(1.f - x * x + 1e-6f);
            entS += ls;
        }
        lp -= 8.f * 0.5f * LOG2PI_F;
        entS += 8.f * (0.5f + 0.5f * LOG2PI_F);
        const int r = t * 1024 + b0 + bb;
        out[r] = lp - lj;
        out[TB_ + r] = entS + lj;
        out[2 * TB_ + r] = hp[0];
    }
}

extern "C" void kernel_launch(void* const* d_in, const int* in_sizes, int n_in,
                              void* d_out, int out_size, void* d_ws, size_t ws_size,
                              hipStream_t stream) {
    const float* obs   = (const float*)d_in[0];
    const float* acts  = (const float*)d_in[1];
    const float* dones = (const float*)d_in[2];
    const float* h0    = (const float*)d_in[3];
    const float* c0    = (const float*)d_in[4];
    const float* w1    = (const float*)d_in[5];
    const float* b1    = (const float*)d_in[6];
    const float* w2    = (const float*)d_in[7];
    const float* b2    = (const float*)d_in[8];
    const float* wih   = (const float*)d_in[9];
    const float* whh   = (const float*)d_in[10];
    const float* bih   = (const float*)d_in[11];
    const float* bhh   = (const float*)d_in[12];
    const float* amw   = (const float*)d_in[13];
    const float* amb   = (const float*)d_in[14];
    const float* lstd  = (const float*)d_in[15];
    const float* crw   = (const float*)d_in[16];
    const float* crb   = (const float*)d_in[17];
    float* out = (float*)d_out;
    (void)d_ws; (void)ws_size;

    hipLaunchKernelGGL(fused_kernel, dim3(256), dim3(1024), 0, stream,
                       obs, whh, wih, h0, c0, bhh, bih, dones,
                       amw, crw, amb, crb, w1, b1, w2, b2, lstd, acts, out);
}

// Round 7
// 225.139 us; speedup vs baseline: 5.2171x; 5.2171x over previous
//
#include <hip/hip_runtime.h>

typedef float f32x4 __attribute__((ext_vector_type(4)));
typedef short short8 __attribute__((ext_vector_type(8)));
typedef short s16x4 __attribute__((ext_vector_type(4)));

#define MFMA16(a, b, c) __builtin_amdgcn_mfma_f32_16x16x32_bf16((a), (b), (c), 0, 0, 0)

#define T_ 256
#define B_ 1024
#define H_ 128
#define TB_ 262144
#define BH_ 131072
#define LOG2PI_F 1.8378770664093453f

__device__ inline short f2bf(float f) {
    unsigned u = __builtin_bit_cast(unsigned, f);
    u += 0x7fffu + ((u >> 16) & 1u);
    return (short)(u >> 16);
}
__device__ inline float fexp(float x) { return __builtin_amdgcn_exp2f(x * 1.4426950408889634f); }
__device__ inline float fsigm(float x) { return __builtin_amdgcn_rcpf(1.f + fexp(-x)); }
__device__ inline float ftanh(float x) { return 1.f - 2.f * __builtin_amdgcn_rcpf(fexp(2.f * x) + 1.f); }

__device__ inline short8 pack8(float4 u0, float4 u1) {
    short8 p;
    p[0] = f2bf(u0.x); p[1] = f2bf(u0.y); p[2] = f2bf(u0.z); p[3] = f2bf(u0.w);
    p[4] = f2bf(u1.x); p[5] = f2bf(u1.y); p[6] = f2bf(u1.z); p[7] = f2bf(u1.w);
    return p;
}

// ---------------- EX: encoder only (obs -> x2), 64-row tiles; weights converted in-reg ----------------
// x2 layout: idx = ((t*256 + (b>>2))*4 + (b&3))*128 + dim   (1KB per (t, lstm-WG))
__global__ __launch_bounds__(512, 4) void ex_kernel(
    const float* __restrict__ obs, const float* __restrict__ eb1,
    const float* __restrict__ eb2,
    const float* __restrict__ w1f, const float* __restrict__ w2f,
    short* __restrict__ x2p)
{
    __shared__ __align__(16) short xtA[64 * 128];  // obs ping
    __shared__ __align__(16) short xtB[64 * 128];  // obs pong
    __shared__ __align__(16) short xtC[64 * 128];  // x1
    const int tid = threadIdx.x;
    const int l = tid & 63, w = tid >> 6;
    const int l15 = l & 15, kg = l >> 4;
    const int srow = tid >> 3, sln = tid & 7;      // staging: 8 threads/row
    const int ssw = (srow & 7) << 3;

    short8 fw1[4], fw2[4];
#pragma unroll
    for (int kk = 0; kk < 4; ++kk) {
        const float* s1 = w1f + (w * 16 + l15) * 128 + kk * 32 + 8 * kg;
        const float* s2 = w2f + (w * 16 + l15) * 128 + kk * 32 + 8 * kg;
        fw1[kk] = pack8(*(const float4*)s1, *(const float4*)(s1 + 4));
        fw2[kk] = pack8(*(const float4*)s2, *(const float4*)(s2 + 4));
        asm volatile("" : "+v"(fw1[kk]), "+v"(fw2[kk]));
    }
    const float bb1 = eb1[w * 16 + l15], bb2 = eb2[w * 16 + l15];

    const int NT = 8;  // 64-row tiles per block; 512 blocks x 8 = 4096 tiles
    const int t0 = blockIdx.x * NT;

    {
        const float* src = obs + ((size_t)t0 * 64 + srow) * 128 + sln * 16;
#pragma unroll
        for (int ii = 0; ii < 2; ++ii) {
            float4 v0 = *(const float4*)(src + ii * 8);
            float4 v1 = *(const float4*)(src + ii * 8 + 4);
            *(short8*)(xtA + srow * 128 + ((sln * 16 + ii * 8) ^ ssw)) = pack8(v0, v1);
        }
    }
    __syncthreads();

    for (int i = 0; i < NT; ++i) {
        const int tile = t0 + i;
        short* bufO = (i & 1) ? xtB : xtA;
        short* bufN = (i & 1) ? xtA : xtB;

        float4 pf[4];
        {
            const int tn = (i + 1 < NT) ? tile + 1 : tile;
            const float* src = obs + ((size_t)tn * 64 + srow) * 128 + sln * 16;
#pragma unroll
            for (int ii = 0; ii < 4; ++ii) pf[ii] = *(const float4*)(src + ii * 4);
        }

        // G1: obs -> x1 (tanh)
#pragma unroll
        for (int mf = 0; mf < 4; ++mf) {
            const int ra = mf * 16 + l15, swa = (ra & 7) << 3;
            short8 a[4];
#pragma unroll
            for (int kk = 0; kk < 4; ++kk)
                a[kk] = *(const short8*)&bufO[ra * 128 + ((kk * 32 + 8 * kg) ^ swa)];
            f32x4 acc = {bb1, bb1, bb1, bb1};
#pragma unroll
            for (int kk = 0; kk < 4; ++kk) acc = MFMA16(a[kk], fw1[kk], acc);
#pragma unroll
            for (int j = 0; j < 4; ++j) {
                int rw = mf * 16 + kg * 4 + j;
                xtC[rw * 128 + ((w * 16 + l15) ^ ((rw & 7) << 3))] = f2bf(ftanh(acc[j]));
            }
        }
        __syncthreads();

        // G2: x1 -> x2 (tanh), direct global stores in lstm layout; also write obsN
        const int t = (tile * 64) >> 10;
        const int b_base = (tile * 64) & 1023;
#pragma unroll
        for (int mf = 0; mf < 4; ++mf) {
            const int ra = mf * 16 + l15, swa = (ra & 7) << 3;
            short8 a[4];
#pragma unroll
            for (int kk = 0; kk < 4; ++kk)
                a[kk] = *(const short8*)&xtC[ra * 128 + ((kk * 32 + 8 * kg) ^ swa)];
            f32x4 acc = {bb2, bb2, bb2, bb2};
#pragma unroll
            for (int kk = 0; kk < 4; ++kk) acc = MFMA16(a[kk], fw2[kk], acc);
#pragma unroll
            for (int j = 0; j < 4; ++j) {
                int b = b_base + mf * 16 + kg * 4 + j;
                size_t idx = (((size_t)t * 256 + (b >> 2)) * 4 + (b & 3)) * 128 + w * 16 + l15;
                x2p[idx] = f2bf(ftanh(acc[j]));
            }
        }
#pragma unroll
        for (int ii = 0; ii < 2; ++ii) {
            *(short8*)(bufN + srow * 128 + ((sln * 16 + ii * 8) ^ ssw)) =
                pack8(pf[ii * 2], pf[ii * 2 + 1]);
        }
        __syncthreads();
    }
}

// ---------------- R: LSTM + fused heads + fused logprob epilogue ----------------
// 4 rows/WG, 8 waves, 256 WGs. h-A rows quad-replicated (batch = row>>2) so all 4 C-regs
// of lane (kg,l15) hold batch kg. xg kept in f32 regs; xgC[s] fed as MFMA C-in. x-chain
// A-frags (xfr) loaded from LDS ONCE per 4-step group (buffer is stable), reused 4 steps.
// Unmasked h2 in a 16-slot LDS ring; every 8th step all 8 waves each compute one past
// timestep's 9-dim head into LDS hd (48KB). Post-scan: in-WG logprob/entropy/value epilogue.
__global__ __launch_bounds__(512) void lstm_kernel(
    const short* __restrict__ x2p, const float* __restrict__ whh,
    const float* __restrict__ wih,
    const float* __restrict__ h0, const float* __restrict__ c0,
    const float* __restrict__ bhh, const float* __restrict__ bih,
    const float* __restrict__ dones,
    const float* __restrict__ amw, const float* __restrict__ crw,
    const float* __restrict__ amb, const float* __restrict__ crb,
    const float* __restrict__ lstd, const float* __restrict__ actions,
    float* __restrict__ out)
{
    __shared__ __align__(16) short hbuf[2][4 * 160];   // masked h dbuf (MFMA A source)
    __shared__ __align__(16) short hring[16 * 640];    // unmasked h2 ring [slot][4*160]
    __shared__ __align__(16) short x2b[2][16 * 160];   // x2 group slots (XOR-swizzled)
    __shared__ float dlds[1028];                       // masks [t][j]
    __shared__ float hd[1024 * 12];                    // head results [t*4+kg][12] f32 (48KB)
    const int tid = threadIdx.x;
    const int l = tid & 63, w = tid >> 6;
    const int l15 = l & 15, kg = l >> 4;
    const int b0 = blockIdx.x * 4;
    const int d = w * 16 + l15;
    const int blk = blockIdx.x;
    const int xsw = (l15 & 7) << 3;                    // x2b read-side XOR swizzle

    // persistent w_hh + w_ih B-frags, converted in-reg from f32 (+ anti-remat pin)
    short8 bfr[4][4], bfi[4][4];
#pragma unroll
    for (int s = 0; s < 4; ++s)
#pragma unroll
        for (int kk = 0; kk < 4; ++kk) {
            const float* sr = whh + ((s * 128 + d) * 128 + kk * 32 + 8 * kg);
            const float* si = wih + ((s * 128 + d) * 128 + kk * 32 + 8 * kg);
            bfr[s][kk] = pack8(*(const float4*)sr, *(const float4*)(sr + 4));
            bfi[s][kk] = pack8(*(const float4*)si, *(const float4*)(si + 4));
            asm volatile("" : "+v"(bfr[s][kk]), "+v"(bfi[s][kk]));
        }

    // head B-frags: row l15: 0 = cr_w, 1..8 = am_w[l15-1], 9..15 = 0
    short8 hb4[4];
#pragma unroll
    for (int kk = 0; kk < 4; ++kk) {
        if (l15 == 0) {
            const float* s0 = crw + kk * 32 + 8 * kg;
            hb4[kk] = pack8(*(const float4*)s0, *(const float4*)(s0 + 4));
        } else if (l15 <= 8) {
            const float* s0 = amw + (l15 - 1) * 128 + kk * 32 + 8 * kg;
            hb4[kk] = pack8(*(const float4*)s0, *(const float4*)(s0 + 4));
        } else {
            hb4[kk] = short8{0, 0, 0, 0, 0, 0, 0, 0};
        }
        asm volatile("" : "+v"(hb4[kk]));
    }
    const float biasH = (l15 == 0) ? crb[0] : (l15 <= 8 ? amb[l15 - 1] : 0.f);

    for (int i = tid; i < 1028; i += 512) {
        int t = i >> 2, jj = i & 3;
        dlds[i] = (t < 256) ? 1.f - dones[t * 1024 + b0 + jj] : 1.f;
    }

    float bh[4];
#pragma unroll
    for (int s = 0; s < 4; ++s) bh[s] = bhh[s * 128 + d] + bih[s * 128 + d];

    // x2 staging: thread tid owns 8B: t_off=tid>>7, j=(tid>>5)&3, dim=(tid&31)*4
    const int st_toff = tid >> 7, st_j = (tid >> 5) & 3, st_dim = (tid & 31) * 4;
    const int st_row = st_j * 4 + st_toff;
    const int xrow160 = st_row * 160 + (st_dim ^ ((st_row & 7) << 3));  // swizzled write addr
#define X2GIDX(G) ((((size_t)(((G) * 4 + st_toff) <= 255 ? ((G) * 4 + st_toff) : 255) * 256 + blk) * 4 + st_j) * 128 + st_dim)

    // prologue: stage g0 -> x2b[0], g1 -> x2b[1]; issue g2 -> xpf
    {
        s16x4 v0 = *(const s16x4*)(x2p + X2GIDX(0));
        s16x4 v1 = *(const s16x4*)(x2p + X2GIDX(1));
        *(s16x4*)&x2b[0][xrow160] = v0;
        *(s16x4*)&x2b[1][xrow160] = v1;
    }
    s16x4 xpf = *(const s16x4*)(x2p + X2GIDX(2));
    asm volatile("s_waitcnt lgkmcnt(0)" ::: "memory");
    __syncthreads();

    // prologue x-chains for g0 (from x2b[0]) -> xgA, bh folded into C-init
    f32x4 xgA[4], xgB[4];
#pragma unroll
    for (int s = 0; s < 4; ++s) {
        short8 ax[4];
#pragma unroll
        for (int kk = 0; kk < 4; ++kk)
            ax[kk] = *(const short8*)&x2b[0][l15 * 160 + ((kk * 32 + kg * 8) ^ xsw)];
        f32x4 accX = {bh[s], bh[s], bh[s], bh[s]};
#pragma unroll
        for (int kk = 0; kk < 4; ++kk) accX = MFMA16(ax[kk], bfi[s][kk], accX);
        xgA[s] = accX;
    }

    float h = h0[(b0 + kg) * 128 + d];
    float c = c0[(b0 + kg) * 128 + d];
    hbuf[0][kg * 160 + d] = f2bf(h * dlds[kg]);
    asm volatile("s_waitcnt lgkmcnt(0)" ::: "memory");
    __syncthreads();

    const int aoff = (l15 >> 2) * 160;  // quad-replicated A rows: batch = row>>2
    float mreg = dlds[kg];

    // x-chain A-frag cache: loaded at group start (XLOAD), reused for the 4 steps
    short8 xfr[4];

    // one LSTM step; DO_HEAD: all 8 waves each do one past step's head (t-8+w) into hd LDS
#define LSTM_STEP(t, hb, i_s, xgC, xgN, x2R, XLOAD, DO_T3, GNEXT, DO_HEAD)                 \
    {                                                                                      \
        short8 a[4];                                                                       \
        _Pragma("unroll")                                                                  \
        for (int kk = 0; kk < 4; ++kk)                                                     \
            a[kk] = *(const short8*)&hbuf[hb][aoff + kk * 32 + kg * 8];                    \
        f32x4 acc[4];                                                                      \
        _Pragma("unroll")                                                                  \
        for (int s = 0; s < 4; ++s) acc[s] = xgC[s];                                       \
        _Pragma("unroll")                                                                  \
        for (int kk = 0; kk < 4; ++kk)                                                     \
            _Pragma("unroll")                                                              \
            for (int s = 0; s < 4; ++s) acc[s] = MFMA16(a[kk], bfr[s][kk], acc[s]);        \
        if (XLOAD) { /* load group's x-frags once; buffer stable for all 4 steps */        \
            _Pragma("unroll")                                                              \
            for (int kk = 0; kk < 4; ++kk)                                                 \
                xfr[kk] = *(const short8*)&x2R[l15 * 160 + ((kk * 32 + kg * 8) ^ xsw)];    \
        }                                                                                  \
        { /* x-chain: gate i_s of next group, full M=16, bh folded into C-init */          \
            f32x4 accX = {bh[i_s], bh[i_s], bh[i_s], bh[i_s]};                             \
            _Pragma("unroll")                                                              \
            for (int kk = 0; kk < 4; ++kk) accX = MFMA16(xfr[kk], bfi[i_s][kk], accX);     \
            xgN[i_s] = accX;                                                               \
        }                                                                                  \
        if (DO_HEAD) { /* head for step th = t-8+w, from ring slot th&15 */                \
            int th = (t) - 8 + w;                                                          \
            const short* hr = &hring[(th & 15) * 640];                                     \
            short8 ah[4];                                                                  \
            _Pragma("unroll")                                                              \
            for (int kk = 0; kk < 4; ++kk)                                                 \
                ah[kk] = *(const short8*)&hr[aoff + kk * 32 + kg * 8];                     \
            f32x4 aH = {biasH, biasH, biasH, biasH};                                       \
            _Pragma("unroll")                                                              \
            for (int kk = 0; kk < 4; ++kk) aH = MFMA16(ah[kk], hb4[kk], aH);               \
            if (l15 < 9) hd[((th) * 4 + kg) * 12 + l15] = aH[0];                           \
        }                                                                                  \
        if (DO_T3) {                                                                      \
            *(s16x4*)&x2W[xrow160] = xpf;                                                  \
            xpf = *(const s16x4*)(x2p + X2GIDX(GNEXT));                                    \
        }                                                                                  \
        float mn = dlds[((t) + 1) * 4 + kg];                                               \
        float gi = acc[0][i_s];                                                            \
        float gf = acc[1][i_s];                                                            \
        float gg = acc[2][i_s];                                                            \
        float go = acc[3][i_s];                                                            \
        c = fsigm(gf) * (c * mreg) + fsigm(gi) * ftanh(gg);                                \
        float h2 = fsigm(go) * ftanh(c);                                                   \
        h = h2;                                                                            \
        mreg = mn;                                                                         \
        hbuf[(hb) ^ 1][kg * 160 + d] = f2bf(h2 * mn);                                      \
        hring[((t) & 15) * 640 + kg * 160 + d] = f2bf(h2);                                 \
        asm volatile("s_waitcnt lgkmcnt(0)" ::: "memory");                                 \
        __builtin_amdgcn_s_barrier();                                                      \
        asm volatile("" ::: "memory");                                                     \
    }

    for (int g = 0; g < 64; g += 2) {
        {   // even group g: consume xgA, produce xgB from x2b[1] (group g+1)
            const int tb = g * 4;
            const short* x2R = &x2b[1][0];
            short* x2W = &x2b[0][0];   // at t3: stage group g+2 into slot 0
            LSTM_STEP(tb + 0, 0, 0, xgA, xgB, x2R, 1, 0, 0, (g > 0));
            LSTM_STEP(tb + 1, 1, 1, xgA, xgB, x2R, 0, 0, 0, 0);
            LSTM_STEP(tb + 2, 0, 2, xgA, xgB, x2R, 0, 0, 0, 0);
            LSTM_STEP(tb + 3, 1, 3, xgA, xgB, x2R, 0, 1, (g + 3), 0);
        }
        {   // odd group g+1: consume xgB, produce xgA from x2b[0] (group g+2)
            const int tb = (g + 1) * 4;
            const short* x2R = &x2b[0][0];
            short* x2W = &x2b[1][0];   // at t3: stage group g+3 into slot 1
            LSTM_STEP(tb + 0, 0, 0, xgB, xgA, x2R, 1, 0, 0, 0);
            LSTM_STEP(tb + 1, 1, 1, xgB, xgA, x2R, 0, 0, 0, 0);
            LSTM_STEP(tb + 2, 0, 2, xgB, xgA, x2R, 0, 0, 0, 0);
            LSTM_STEP(tb + 3, 1, 3, xgB, xgA, x2R, 0, 1, (g + 4), 0);
        }
    }
#undef LSTM_STEP
#undef X2GIDX

    // final heads for t = 248..255 (ring slots 8..15), all 8 waves, one step each
    {
        int th = 248 + w;
        const short* hr = &hring[(th & 15) * 640];
        short8 ah[4];
#pragma unroll
        for (int kk = 0; kk < 4; ++kk)
            ah[kk] = *(const short8*)&hr[aoff + kk * 32 + kg * 8];
        f32x4 aH = {biasH, biasH, biasH, biasH};
#pragma unroll
        for (int kk = 0; kk < 4; ++kk) aH = MFMA16(ah[kk], hb4[kk], aH);
        if (l15 < 9) hd[(th * 4 + kg) * 12 + l15] = aH[0];
    }

    out[3 * TB_ + (b0 + kg) * 128 + d] = h;
    out[3 * TB_ + BH_ + (b0 + kg) * 128 + d] = c;

    // ---- fused logprob/entropy/value epilogue (was headepi_kernel) ----
    __syncthreads();
    for (int rr = tid; rr < 1024; rr += 512) {
        const int t = rr >> 2, bb = rr & 3;
        const float* hp = &hd[rr * 12];
        const float* ap = actions + ((size_t)t * 1024 + b0 + bb) * 8;
        float4 a0 = *(const float4*)(ap);
        float4 a1 = *(const float4*)(ap + 4);
        float act[8] = {a0.x, a0.y, a0.z, a0.w, a1.x, a1.y, a1.z, a1.w};
        float lp = 0.f, lj = 0.f, entS = 0.f;
#pragma unroll
        for (int ai = 0; ai < 8; ++ai) {
            float x = act[ai];
            float xc = fminf(fmaxf(x, -1.f + 1e-6f), 1.f - 1e-6f);
            float u = 0.5f * logf((1.f + xc) / (1.f - xc));
            float ls = lstd[ai];
            float z = (u - hp[1 + ai]) * expf(-ls);
            lp += -0.5f * z * z - ls;
            lj += logf(1.f - x * x + 1e-6f);
            entS += ls;
        }
        lp -= 8.f * 0.5f * LOG2PI_F;
        entS += 8.f * (0.5f + 0.5f * LOG2PI_F);
        const int r = t * 1024 + b0 + bb;
        out[r] = lp - lj;
        out[TB_ + r] = entS + lj;
        out[2 * TB_ + r] = hp[0];
    }
}

extern "C" void kernel_launch(void* const* d_in, const int* in_sizes, int n_in,
                              void* d_out, int out_size, void* d_ws, size_t ws_size,
                              hipStream_t stream) {
    const float* obs   = (const float*)d_in[0];
    const float* acts  = (const float*)d_in[1];
    const float* dones = (const float*)d_in[2];
    const float* h0    = (const float*)d_in[3];
    const float* c0    = (const float*)d_in[4];
    const float* w1    = (const float*)d_in[5];
    const float* b1    = (const float*)d_in[6];
    const float* w2    = (const float*)d_in[7];
    const float* b2    = (const float*)d_in[8];
    const float* wih   = (const float*)d_in[9];
    const float* whh   = (const float*)d_in[10];
    const float* bih   = (const float*)d_in[11];
    const float* bhh   = (const float*)d_in[12];
    const float* amw   = (const float*)d_in[13];
    const float* amb   = (const float*)d_in[14];
    const float* lstd  = (const float*)d_in[15];
    const float* crw   = (const float*)d_in[16];
    const float* crb   = (const float*)d_in[17];
    float* out = (float*)d_out;

    short* x2p = (short*)d_ws;               // 64 MB  [t][blk][j][dim] bf16
    if (ws_size < (size_t)67108864) return;

    hipLaunchKernelGGL(ex_kernel, dim3(512), dim3(512), 0, stream,
                       obs, b1, b2, w1, w2, x2p);
    hipLaunchKernelGGL(lstm_kernel, dim3(256), dim3(512), 0, stream,
                       x2p, whh, wih, h0, c0, bhh, bih, dones,
                       amw, crw, amb, crb, lstd, acts, out);
}

// Round 8
// 212.752 us; speedup vs baseline: 5.5208x; 1.0582x over previous
//
#include <hip/hip_runtime.h>

typedef float f32x4 __attribute__((ext_vector_type(4)));
typedef short short8 __attribute__((ext_vector_type(8)));
typedef short s16x4 __attribute__((ext_vector_type(4)));

#define MFMA16(a, b, c) __builtin_amdgcn_mfma_f32_16x16x32_bf16((a), (b), (c), 0, 0, 0)

#define T_ 256
#define B_ 1024
#define H_ 128
#define TB_ 262144
#define BH_ 131072
#define LOG2PI_F 1.8378770664093453f
#define LN2_F 0.6931471805599453f
#define LOG2E_F 1.4426950408889634f

__device__ inline short f2bf(float f) {
    unsigned u = __builtin_bit_cast(unsigned, f);
    u += 0x7fffu + ((u >> 16) & 1u);
    return (short)(u >> 16);
}
__device__ inline float fexp(float x) { return __builtin_amdgcn_exp2f(x * LOG2E_F); }
__device__ inline float fsigm(float x) { return __builtin_amdgcn_rcpf(1.f + fexp(-x)); }
__device__ inline float ftanh(float x) { return 1.f - 2.f * __builtin_amdgcn_rcpf(fexp(2.f * x) + 1.f); }

__device__ inline short8 pack8(float4 u0, float4 u1) {
    short8 p;
    p[0] = f2bf(u0.x); p[1] = f2bf(u0.y); p[2] = f2bf(u0.z); p[3] = f2bf(u0.w);
    p[4] = f2bf(u1.x); p[5] = f2bf(u1.y); p[6] = f2bf(u1.z); p[7] = f2bf(u1.w);
    return p;
}

// ---------------- EX: encoder only (obs -> x2), 64-row tiles; weights converted in-reg ----------------
// x2 layout: idx = ((t*256 + (b>>2))*4 + (b&3))*128 + dim   (1KB per (t, lstm-WG))
__global__ __launch_bounds__(512, 4) void ex_kernel(
    const float* __restrict__ obs, const float* __restrict__ eb1,
    const float* __restrict__ eb2,
    const float* __restrict__ w1f, const float* __restrict__ w2f,
    short* __restrict__ x2p)
{
    __shared__ __align__(16) short xtA[64 * 128];  // obs ping
    __shared__ __align__(16) short xtB[64 * 128];  // obs pong
    __shared__ __align__(16) short xtC[64 * 128];  // x1
    const int tid = threadIdx.x;
    const int l = tid & 63, w = tid >> 6;
    const int l15 = l & 15, kg = l >> 4;
    const int srow = tid >> 3, sln = tid & 7;      // staging: 8 threads/row
    const int ssw = (srow & 7) << 3;

    short8 fw1[4], fw2[4];
#pragma unroll
    for (int kk = 0; kk < 4; ++kk) {
        const float* s1 = w1f + (w * 16 + l15) * 128 + kk * 32 + 8 * kg;
        const float* s2 = w2f + (w * 16 + l15) * 128 + kk * 32 + 8 * kg;
        fw1[kk] = pack8(*(const float4*)s1, *(const float4*)(s1 + 4));
        fw2[kk] = pack8(*(const float4*)s2, *(const float4*)(s2 + 4));
        asm volatile("" : "+v"(fw1[kk]), "+v"(fw2[kk]));
    }
    const float bb1 = eb1[w * 16 + l15], bb2 = eb2[w * 16 + l15];

    const int NT = 8;  // 64-row tiles per block; 512 blocks x 8 = 4096 tiles
    const int t0 = blockIdx.x * NT;

    {
        const float* src = obs + ((size_t)t0 * 64 + srow) * 128 + sln * 16;
#pragma unroll
        for (int ii = 0; ii < 2; ++ii) {
            float4 v0 = *(const float4*)(src + ii * 8);
            float4 v1 = *(const float4*)(src + ii * 8 + 4);
            *(short8*)(xtA + srow * 128 + ((sln * 16 + ii * 8) ^ ssw)) = pack8(v0, v1);
        }
    }
    __syncthreads();

    for (int i = 0; i < NT; ++i) {
        const int tile = t0 + i;
        short* bufO = (i & 1) ? xtB : xtA;
        short* bufN = (i & 1) ? xtA : xtB;

        float4 pf[4];
        {
            const int tn = (i + 1 < NT) ? tile + 1 : tile;
            const float* src = obs + ((size_t)tn * 64 + srow) * 128 + sln * 16;
#pragma unroll
            for (int ii = 0; ii < 4; ++ii) pf[ii] = *(const float4*)(src + ii * 4);
        }

        // G1: obs -> x1 (tanh)
#pragma unroll
        for (int mf = 0; mf < 4; ++mf) {
            const int ra = mf * 16 + l15, swa = (ra & 7) << 3;
            short8 a[4];
#pragma unroll
            for (int kk = 0; kk < 4; ++kk)
                a[kk] = *(const short8*)&bufO[ra * 128 + ((kk * 32 + 8 * kg) ^ swa)];
            f32x4 acc = {bb1, bb1, bb1, bb1};
#pragma unroll
            for (int kk = 0; kk < 4; ++kk) acc = MFMA16(a[kk], fw1[kk], acc);
#pragma unroll
            for (int j = 0; j < 4; ++j) {
                int rw = mf * 16 + kg * 4 + j;
                xtC[rw * 128 + ((w * 16 + l15) ^ ((rw & 7) << 3))] = f2bf(ftanh(acc[j]));
            }
        }
        __syncthreads();

        // G2: x1 -> x2 (tanh), direct global stores in lstm layout; also write obsN
        const int t = (tile * 64) >> 10;
        const int b_base = (tile * 64) & 1023;
#pragma unroll
        for (int mf = 0; mf < 4; ++mf) {
            const int ra = mf * 16 + l15, swa = (ra & 7) << 3;
            short8 a[4];
#pragma unroll
            for (int kk = 0; kk < 4; ++kk)
                a[kk] = *(const short8*)&xtC[ra * 128 + ((kk * 32 + 8 * kg) ^ swa)];
            f32x4 acc = {bb2, bb2, bb2, bb2};
#pragma unroll
            for (int kk = 0; kk < 4; ++kk) acc = MFMA16(a[kk], fw2[kk], acc);
#pragma unroll
            for (int j = 0; j < 4; ++j) {
                int b = b_base + mf * 16 + kg * 4 + j;
                size_t idx = (((size_t)t * 256 + (b >> 2)) * 4 + (b & 3)) * 128 + w * 16 + l15;
                x2p[idx] = f2bf(ftanh(acc[j]));
            }
        }
#pragma unroll
        for (int ii = 0; ii < 2; ++ii) {
            *(short8*)(bufN + srow * 128 + ((sln * 16 + ii * 8) ^ ssw)) =
                pack8(pf[ii * 2], pf[ii * 2 + 1]);
        }
        __syncthreads();
    }
}

// ---------------- R: LSTM + fused heads + fused logprob epilogue ----------------
// 4 rows/WG, 8 waves, 256 WGs. h-A rows quad-replicated (batch = row>>2) so all 4 C-regs
// of lane (kg,l15) hold batch kg. xg kept in f32 regs; xgC[s] fed as MFMA C-in. Per-step
// x2b frag reads (R7 showed group-caching them regresses: reads are latency-hidden).
// Unmasked h2 in a 16-slot LDS ring; every 8th step all 8 waves each compute one past
// timestep's 9-dim head into LDS hd (48KB). Post-scan: in-WG logprob epilogue (HW log/exp).
__global__ __launch_bounds__(512) void lstm_kernel(
    const short* __restrict__ x2p, const float* __restrict__ whh,
    const float* __restrict__ wih,
    const float* __restrict__ h0, const float* __restrict__ c0,
    const float* __restrict__ bhh, const float* __restrict__ bih,
    const float* __restrict__ dones,
    const float* __restrict__ amw, const float* __restrict__ crw,
    const float* __restrict__ amb, const float* __restrict__ crb,
    const float* __restrict__ lstd, const float* __restrict__ actions,
    float* __restrict__ out)
{
    __shared__ __align__(16) short hbuf[2][4 * 160];   // masked h dbuf (MFMA A source)
    __shared__ __align__(16) short hring[16 * 640];    // unmasked h2 ring [slot][4*160]
    __shared__ __align__(16) short x2b[2][16 * 160];   // x2 group slots (XOR-swizzled)
    __shared__ float dlds[1028];                       // masks [t][j]
    __shared__ float hd[1024 * 12];                    // head results [t*4+kg][12] f32 (48KB)
    const int tid = threadIdx.x;
    const int l = tid & 63, w = tid >> 6;
    const int l15 = l & 15, kg = l >> 4;
    const int b0 = blockIdx.x * 4;
    const int d = w * 16 + l15;
    const int blk = blockIdx.x;
    const int xsw = (l15 & 7) << 3;                    // x2b read-side XOR swizzle

    // persistent w_hh + w_ih B-frags, converted in-reg from f32 (+ anti-remat pin)
    short8 bfr[4][4], bfi[4][4];
#pragma unroll
    for (int s = 0; s < 4; ++s)
#pragma unroll
        for (int kk = 0; kk < 4; ++kk) {
            const float* sr = whh + ((s * 128 + d) * 128 + kk * 32 + 8 * kg);
            const float* si = wih + ((s * 128 + d) * 128 + kk * 32 + 8 * kg);
            bfr[s][kk] = pack8(*(const float4*)sr, *(const float4*)(sr + 4));
            bfi[s][kk] = pack8(*(const float4*)si, *(const float4*)(si + 4));
            asm volatile("" : "+v"(bfr[s][kk]), "+v"(bfi[s][kk]));
        }

    // head B-frags: row l15: 0 = cr_w, 1..8 = am_w[l15-1], 9..15 = 0
    short8 hb4[4];
#pragma unroll
    for (int kk = 0; kk < 4; ++kk) {
        if (l15 == 0) {
            const float* s0 = crw + kk * 32 + 8 * kg;
            hb4[kk] = pack8(*(const float4*)s0, *(const float4*)(s0 + 4));
        } else if (l15 <= 8) {
            const float* s0 = amw + (l15 - 1) * 128 + kk * 32 + 8 * kg;
            hb4[kk] = pack8(*(const float4*)s0, *(const float4*)(s0 + 4));
        } else {
            hb4[kk] = short8{0, 0, 0, 0, 0, 0, 0, 0};
        }
        asm volatile("" : "+v"(hb4[kk]));
    }
    const float biasH = (l15 == 0) ? crb[0] : (l15 <= 8 ? amb[l15 - 1] : 0.f);

    for (int i = tid; i < 1028; i += 512) {
        int t = i >> 2, jj = i & 3;
        dlds[i] = (t < 256) ? 1.f - dones[t * 1024 + b0 + jj] : 1.f;
    }

    float bh[4];
#pragma unroll
    for (int s = 0; s < 4; ++s) bh[s] = bhh[s * 128 + d] + bih[s * 128 + d];

    // x2 staging: thread tid owns 8B: t_off=tid>>7, j=(tid>>5)&3, dim=(tid&31)*4
    const int st_toff = tid >> 7, st_j = (tid >> 5) & 3, st_dim = (tid & 31) * 4;
    const int st_row = st_j * 4 + st_toff;
    const int xrow160 = st_row * 160 + (st_dim ^ ((st_row & 7) << 3));  // swizzled write addr
#define X2GIDX(G) ((((size_t)(((G) * 4 + st_toff) <= 255 ? ((G) * 4 + st_toff) : 255) * 256 + blk) * 4 + st_j) * 128 + st_dim)

    // prologue: stage g0 -> x2b[0], g1 -> x2b[1]; issue g2 -> xpf
    {
        s16x4 v0 = *(const s16x4*)(x2p + X2GIDX(0));
        s16x4 v1 = *(const s16x4*)(x2p + X2GIDX(1));
        *(s16x4*)&x2b[0][xrow160] = v0;
        *(s16x4*)&x2b[1][xrow160] = v1;
    }
    s16x4 xpf = *(const s16x4*)(x2p + X2GIDX(2));
    asm volatile("s_waitcnt lgkmcnt(0)" ::: "memory");
    __syncthreads();

    // prologue x-chains for g0 (from x2b[0]) -> xgA, bh folded into C-init
    f32x4 xgA[4], xgB[4];
#pragma unroll
    for (int s = 0; s < 4; ++s) {
        short8 ax[4];
#pragma unroll
        for (int kk = 0; kk < 4; ++kk)
            ax[kk] = *(const short8*)&x2b[0][l15 * 160 + ((kk * 32 + kg * 8) ^ xsw)];
        f32x4 accX = {bh[s], bh[s], bh[s], bh[s]};
#pragma unroll
        for (int kk = 0; kk < 4; ++kk) accX = MFMA16(ax[kk], bfi[s][kk], accX);
        xgA[s] = accX;
    }

    float h = h0[(b0 + kg) * 128 + d];
    float c = c0[(b0 + kg) * 128 + d];
    hbuf[0][kg * 160 + d] = f2bf(h * dlds[kg]);
    asm volatile("s_waitcnt lgkmcnt(0)" ::: "memory");
    __syncthreads();

    const int aoff = (l15 >> 2) * 160;  // quad-replicated A rows: batch = row>>2
    float mreg = dlds[kg];

    // one LSTM step; DO_HEAD: all 8 waves each do one past step's head (t-8+w) into hd LDS
#define LSTM_STEP(t, hb, i_s, xgC, xgN, x2R, DO_T3, GNEXT, DO_HEAD)                        \
    {                                                                                      \
        short8 a[4];                                                                       \
        _Pragma("unroll")                                                                  \
        for (int kk = 0; kk < 4; ++kk)                                                     \
            a[kk] = *(const short8*)&hbuf[hb][aoff + kk * 32 + kg * 8];                    \
        f32x4 acc[4];                                                                      \
        _Pragma("unroll")                                                                  \
        for (int s = 0; s < 4; ++s) acc[s] = xgC[s];                                       \
        _Pragma("unroll")                                                                  \
        for (int kk = 0; kk < 4; ++kk)                                                     \
            _Pragma("unroll")                                                              \
            for (int s = 0; s < 4; ++s) acc[s] = MFMA16(a[kk], bfr[s][kk], acc[s]);        \
        { /* x-chain: gate i_s of next group, full M=16, bh folded into C-init */          \
            short8 ax[4];                                                                  \
            _Pragma("unroll")                                                              \
            for (int kk = 0; kk < 4; ++kk)                                                 \
                ax[kk] = *(const short8*)&x2R[l15 * 160 + ((kk * 32 + kg * 8) ^ xsw)];     \
            f32x4 accX = {bh[i_s], bh[i_s], bh[i_s], bh[i_s]};                             \
            _Pragma("unroll")                                                              \
            for (int kk = 0; kk < 4; ++kk) accX = MFMA16(ax[kk], bfi[i_s][kk], accX);      \
            xgN[i_s] = accX;                                                               \
        }                                                                                  \
        if (DO_HEAD) { /* head for step th = t-8+w, from ring slot th&15 */                \
            int th = (t) - 8 + w;                                                          \
            const short* hr = &hring[(th & 15) * 640];                                     \
            short8 ah[4];                                                                  \
            _Pragma("unroll")                                                              \
            for (int kk = 0; kk < 4; ++kk)                                                 \
                ah[kk] = *(const short8*)&hr[aoff + kk * 32 + kg * 8];                     \
            f32x4 aH = {biasH, biasH, biasH, biasH};                                       \
            _Pragma("unroll")                                                              \
            for (int kk = 0; kk < 4; ++kk) aH = MFMA16(ah[kk], hb4[kk], aH);               \
            if (l15 < 9) hd[((th) * 4 + kg) * 12 + l15] = aH[0];                           \
        }                                                                                  \
        if (DO_T3) {                                                                      \
            *(s16x4*)&x2W[xrow160] = xpf;                                                  \
            xpf = *(const s16x4*)(x2p + X2GIDX(GNEXT));                                    \
        }                                                                                  \
        float mn = dlds[((t) + 1) * 4 + kg];                                               \
        float gi = acc[0][i_s];                                                            \
        float gf = acc[1][i_s];                                                            \
        float gg = acc[2][i_s];                                                            \
        float go = acc[3][i_s];                                                            \
        c = fsigm(gf) * (c * mreg) + fsigm(gi) * ftanh(gg);                                \
        float h2 = fsigm(go) * ftanh(c);                                                   \
        h = h2;                                                                            \
        mreg = mn;                                                                         \
        hbuf[(hb) ^ 1][kg * 160 + d] = f2bf(h2 * mn);                                      \
        hring[((t) & 15) * 640 + kg * 160 + d] = f2bf(h2);                                 \
        asm volatile("s_waitcnt lgkmcnt(0)" ::: "memory");                                 \
        __builtin_amdgcn_s_barrier();                                                      \
        asm volatile("" ::: "memory");                                                     \
    }

    for (int g = 0; g < 64; g += 2) {
        {   // even group g: consume xgA, produce xgB from x2b[1] (group g+1)
            const int tb = g * 4;
            const short* x2R = &x2b[1][0];
            short* x2W = &x2b[0][0];   // at t3: stage group g+2 into slot 0
            LSTM_STEP(tb + 0, 0, 0, xgA, xgB, x2R, 0, 0, (g > 0));
            LSTM_STEP(tb + 1, 1, 1, xgA, xgB, x2R, 0, 0, 0);
            LSTM_STEP(tb + 2, 0, 2, xgA, xgB, x2R, 0, 0, 0);
            LSTM_STEP(tb + 3, 1, 3, xgA, xgB, x2R, 1, (g + 3), 0);
        }
        {   // odd group g+1: consume xgB, produce xgA from x2b[0] (group g+2)
            const int tb = (g + 1) * 4;
            const short* x2R = &x2b[0][0];
            short* x2W = &x2b[1][0];   // at t3: stage group g+3 into slot 1
            LSTM_STEP(tb + 0, 0, 0, xgB, xgA, x2R, 0, 0, 0);
            LSTM_STEP(tb + 1, 1, 1, xgB, xgA, x2R, 0, 0, 0);
            LSTM_STEP(tb + 2, 0, 2, xgB, xgA, x2R, 0, 0, 0);
            LSTM_STEP(tb + 3, 1, 3, xgB, xgA, x2R, 1, (g + 4), 0);
        }
    }
#undef LSTM_STEP
#undef X2GIDX

    // final heads for t = 248..255 (ring slots 8..15), all 8 waves, one step each
    {
        int th = 248 + w;
        const short* hr = &hring[(th & 15) * 640];
        short8 ah[4];
#pragma unroll
        for (int kk = 0; kk < 4; ++kk)
            ah[kk] = *(const short8*)&hr[aoff + kk * 32 + kg * 8];
        f32x4 aH = {biasH, biasH, biasH, biasH};
#pragma unroll
        for (int kk = 0; kk < 4; ++kk) aH = MFMA16(ah[kk], hb4[kk], aH);
        if (l15 < 9) hd[(th * 4 + kg) * 12 + l15] = aH[0];
    }

    out[3 * TB_ + (b0 + kg) * 128 + d] = h;
    out[3 * TB_ + BH_ + (b0 + kg) * 128 + d] = c;

    // ---- fused logprob/entropy/value epilogue (HW v_log_f32 / v_exp_f32) ----
    __syncthreads();
    for (int rr = tid; rr < 1024; rr += 512) {
        const int t = rr >> 2, bb = rr & 3;
        const float* hp = &hd[rr * 12];
        const float* ap = actions + ((size_t)t * 1024 + b0 + bb) * 8;
        float4 a0 = *(const float4*)(ap);
        float4 a1 = *(const float4*)(ap + 4);
        float act[8] = {a0.x, a0.y, a0.z, a0.w, a1.x, a1.y, a1.z, a1.w};
        float lp = 0.f, lj = 0.f, entS = 0.f;
#pragma unroll
        for (int ai = 0; ai < 8; ++ai) {
            float x = act[ai];
            float xc = fminf(fmaxf(x, -1.f + 1e-6f), 1.f - 1e-6f);
            float u = 0.5f * LN2_F *
                      (__builtin_amdgcn_logf(1.f + xc) - __builtin_amdgcn_logf(1.f - xc));
            float ls = lstd[ai];
            float z = (u - hp[1 + ai]) * fexp(-ls);
            lp += -0.5f * z * z - ls;
            lj += LN2_F * __builtin_amdgcn_logf(1.f - x * x + 1e-6f);
            entS += ls;
        }
        lp -= 8.f * 0.5f * LOG2PI_F;
        entS += 8.f * (0.5f + 0.5f * LOG2PI_F);
        const int r = t * 1024 + b0 + bb;
        out[r] = lp - lj;
        out[TB_ + r] = entS + lj;
        out[2 * TB_ + r] = hp[0];
    }
}

extern "C" void kernel_launch(void* const* d_in, const int* in_sizes, int n_in,
                              void* d_out, int out_size, void* d_ws, size_t ws_size,
                              hipStream_t stream) {
    const float* obs   = (const float*)d_in[0];
    const float* acts  = (const float*)d_in[1];
    const float* dones = (const float*)d_in[2];
    const float* h0    = (const float*)d_in[3];
    const float* c0    = (const float*)d_in[4];
    const float* w1    = (const float*)d_in[5];
    const float* b1    = (const float*)d_in[6];
    const float* w2    = (const float*)d_in[7];
    const float* b2    = (const float*)d_in[8];
    const float* wih   = (const float*)d_in[9];
    const float* whh   = (const float*)d_in[10];
    const float* bih   = (const float*)d_in[11];
    const float* bhh   = (const float*)d_in[12];
    const float* amw   = (const float*)d_in[13];
    const float* amb   = (const float*)d_in[14];
    const float* lstd  = (const float*)d_in[15];
    const float* crw   = (const float*)d_in[16];
    const float* crb   = (const float*)d_in[17];
    float* out = (float*)d_out;

    short* x2p = (short*)d_ws;               // 64 MB  [t][blk][j][dim] bf16
    if (ws_size < (size_t)67108864) return;

    hipLaunchKernelGGL(ex_kernel, dim3(512), dim3(512), 0, stream,
                       obs, b1, b2, w1, w2, x2p);
    hipLaunchKernelGGL(lstm_kernel, dim3(256), dim3(512), 0, stream,
                       x2p, whh, wih, h0, c0, bhh, bih, dones,
                       amw, crw, amb, crb, lstd, acts, out);
}